// Round 7
// baseline (305.814 us; speedup 1.0000x reference)
//
#include <hip/hip_runtime.h>
#include <math.h>

#define FDIM 64    // input feature dim
#define CPAD 64    // padded class dim (40 valid), bf16 -> 128B rows
#define NPB  256   // nodes per final bucket (bucket = dst >> 8)
#define RGSH 12    // region shift: region = dst >> 12 (4096 nodes/region)
#define NRGMAX 32
#define CAP1 53248 // entries per region segment (mean ~49.2k, +18 sigma)
#define CAP2B 3456 // entries per bucket segment (mean 3072, +7 sigma)
#define TILE 4096
#define EPT  16    // entries per thread per partition tile (16*256 = TILE)

// ---------------- helpers ----------------

__device__ inline unsigned short f2bf(float f) {
    unsigned int u = __float_as_uint(f);
    unsigned int r = (u + 0x7fffu + ((u >> 16) & 1u)) >> 16;  // RNE
    return (unsigned short)r;
}
__device__ inline float bf_lo(unsigned int v) { return __uint_as_float(v << 16); }
__device__ inline float bf_hi(unsigned int v) { return __uint_as_float(v & 0xffff0000u); }
__device__ inline unsigned int bfpack(float a, float b) {
    return (unsigned int)f2bf(a) | ((unsigned int)f2bf(b) << 16);
}

__global__ __launch_bounds__(256) void k_zero(int* __restrict__ p, int n) {
    int i = blockIdx.x * 256 + threadIdx.x;
    if (i < n) p[i] = 0;
}

// ---------------- pass 1: edges -> 25 regions (LDS-staged, coalesced) ------

__global__ __launch_bounds__(256) void k_part1(const int* __restrict__ src,
                                               const int* __restrict__ dst,
                                               int* __restrict__ rcur,
                                               unsigned int* __restrict__ bin1,
                                               int E, int NR) {
    __shared__ unsigned int sorted[TILE];
    __shared__ int hist[NRGMAX], hbase[NRGMAX], hcur[NRGMAX];
    __shared__ int gbase_s;
    int tid = threadIdx.x;
    int t0 = blockIdx.x * TILE;
    if (tid < NR) { hist[tid] = 0; hcur[tid] = 0; }
    __syncthreads();
    unsigned int ent[EPT]; int rg[EPT];
#pragma unroll
    for (int k = 0; k < EPT; ++k) {
        int i = t0 + k * 256 + tid;
        if (i < E) {
            int s = src[i], d = dst[i];
            ent[k] = ((unsigned int)s << RGSH) | (unsigned int)(d & ((1 << RGSH) - 1));
            rg[k] = d >> RGSH;
            atomicAdd(&hist[rg[k]], 1);
        } else rg[k] = -1;
    }
    __syncthreads();
    if (tid == 0) {
        int acc = 0;
        for (int r = 0; r < NR; ++r) { hbase[r] = acc; acc += hist[r]; }
    }
    __syncthreads();
#pragma unroll
    for (int k = 0; k < EPT; ++k) if (rg[k] >= 0) {
        int p = hbase[rg[k]] + atomicAdd(&hcur[rg[k]], 1);
        sorted[p] = ent[k];
    }
    __syncthreads();
    for (int r = 0; r < NR; ++r) {
        int cnt = hist[r];
        if (cnt == 0) continue;
        if (tid == 0) gbase_s = atomicAdd(&rcur[r], cnt);
        __syncthreads();
        int gb = gbase_s;
        int lim = cnt;
        if (gb + cnt > CAP1) lim = max(0, CAP1 - gb);
        unsigned int* dp = bin1 + (size_t)r * CAP1 + gb;
        const unsigned int* sp = sorted + hbase[r];
        for (int i = tid; i < lim; i += 256) dp[i] = sp[i];
        __syncthreads();
    }
}

// ---------------- pass 2: region -> 16 buckets of 256 nodes ----------------

__global__ __launch_bounds__(256) void k_part2(const int* __restrict__ rcur,
                                               const unsigned int* __restrict__ bin1,
                                               int* __restrict__ bcnt,
                                               unsigned int* __restrict__ bin2) {
    __shared__ unsigned int sorted[TILE];
    __shared__ int hist[16], hbase[16], hcur[16];
    __shared__ int gbase_s;
    int tid = threadIdx.x;
    int r = blockIdx.y;
    int Mr = min(rcur[r], CAP1);
    const unsigned int* seg = bin1 + (size_t)r * CAP1;
    for (int start = blockIdx.x * TILE; start < Mr; start += gridDim.x * TILE) {
        if (tid < 16) { hist[tid] = 0; hcur[tid] = 0; }
        __syncthreads();
        unsigned int ent[EPT]; int bn[EPT];
#pragma unroll
        for (int k = 0; k < EPT; ++k) {
            int i = start + k * 256 + tid;
            if (i < Mr) {
                unsigned int e1 = seg[i];
                bn[k] = (int)((e1 >> 8) & 15u);
                ent[k] = ((e1 >> RGSH) << 8) | (e1 & 255u);  // (src<<8)|(dst&255)
                atomicAdd(&hist[bn[k]], 1);
            } else bn[k] = -1;
        }
        __syncthreads();
        if (tid == 0) {
            int acc = 0;
            for (int q = 0; q < 16; ++q) { hbase[q] = acc; acc += hist[q]; }
        }
        __syncthreads();
#pragma unroll
        for (int k = 0; k < EPT; ++k) if (bn[k] >= 0) {
            int p = hbase[bn[k]] + atomicAdd(&hcur[bn[k]], 1);
            sorted[p] = ent[k];
        }
        __syncthreads();
        for (int q = 0; q < 16; ++q) {
            int cnt = hist[q];
            if (cnt == 0) continue;
            int bucket = (r << 4) + q;
            if (tid == 0) gbase_s = atomicAdd(&bcnt[bucket], cnt);
            __syncthreads();
            int gb = gbase_s;
            int lim = cnt;
            if (gb + cnt > CAP2B) lim = max(0, CAP2B - gb);
            unsigned int* dp = bin2 + (size_t)bucket * CAP2B + gb;
            const unsigned int* sp = sorted + hbase[q];
            for (int i = tid; i < lim; i += 256) dp[i] = sp[i];
            __syncthreads();
        }
    }
}

// ---------------- bucket-count scan -> CSR bases ----------------

__global__ __launch_bounds__(512) void k_bscan(const int* __restrict__ bcnt,
                                               int* __restrict__ cbase,
                                               int* __restrict__ row_ptr,
                                               int NB, int N, int T) {
    __shared__ int lds[512];
    int tid = threadIdx.x;
    int tot = 0;
    if (tid < NB)
        tot = min(bcnt[tid], CAP2B) + min(NPB, N - tid * NPB);  // + self entries
    lds[tid] = tot;
    __syncthreads();
    int val = tot;
#pragma unroll
    for (int off = 1; off < 512; off <<= 1) {
        int o = (tid >= off) ? lds[tid - off] : 0;
        __syncthreads();
        val += o;
        lds[tid] = val;
        __syncthreads();
    }
    if (tid < NB) cbase[tid] = val - tot;   // exclusive
    if (tid == 0) row_ptr[N] = T;
}

// per bucket: local histogram (init 1 = self) + scan -> row_ptr + dinv
__global__ __launch_bounds__(256) void k_build_a(const int* __restrict__ bcnt,
                                                 const int* __restrict__ cbase,
                                                 const unsigned int* __restrict__ bin2,
                                                 int* __restrict__ row_ptr,
                                                 float* __restrict__ dinv, int N) {
    __shared__ int lcnt[256];
    __shared__ int lscan[256];
    int b = blockIdx.x, tid = threadIdx.x;
    int node = (b << 8) + tid;
    lcnt[tid] = (node < N) ? 1 : 0;          // self entry
    __syncthreads();
    int M = min(bcnt[b], CAP2B);
    const unsigned int* seg = bin2 + (size_t)b * CAP2B;
    for (int i = tid; i < M; i += 256)
        atomicAdd(&lcnt[seg[i] & 255u], 1);
    __syncthreads();
    int v = lcnt[tid];
    lscan[tid] = v;
    __syncthreads();
    int val = v;
#pragma unroll
    for (int off = 1; off < 256; off <<= 1) {
        int o = (tid >= off) ? lscan[tid - off] : 0;
        __syncthreads();
        val += o;
        lscan[tid] = val;
        __syncthreads();
    }
    if (node < N) {
        row_ptr[node] = cbase[b] + (val - v);   // exclusive local offset
        dinv[node] = rsqrtf((float)v);          // count includes self entry
    }
}

// per bucket: scatter entries to final CSR slots ({src, w} packed int2)
__global__ __launch_bounds__(256) void k_build_b(const int* __restrict__ bcnt,
                                                 const unsigned int* __restrict__ bin2,
                                                 const int* __restrict__ row_ptr,
                                                 const float* __restrict__ dinv,
                                                 int2* __restrict__ csr, int N) {
    __shared__ int lbase[256];
    __shared__ int lcur[256];
    int b = blockIdx.x, tid = threadIdx.x;
    int node = (b << 8) + tid;
    if (node < N) {
        int base = row_ptr[node];
        lbase[tid] = base;
        float dn = dinv[node];
        csr[base] = make_int2(node, __float_as_int(dn * dn));  // self entry
    } else {
        lbase[tid] = 0;
    }
    lcur[tid] = 1;   // slot 0 taken by self
    __syncthreads();
    int M = min(bcnt[b], CAP2B);
    const unsigned int* seg = bin2 + (size_t)b * CAP2B;
    for (int i = tid; i < M; i += 256) {
        unsigned int en = seg[i];
        int s = (int)(en >> 8);
        int dl = (int)(en & 255u);
        int pos = lbase[dl] + atomicAdd(&lcur[dl], 1);
        float w = dinv[s] * dinv[(b << 8) + dl];
        csr[pos] = make_int2(s, __float_as_int(w));
    }
}

// ---------------- projection: p[n][c] = dot(x[n], W[c]), bf16-packed --------

__global__ __launch_bounds__(256) void k_proj(const float* __restrict__ x,
                                              const float* __restrict__ W,
                                              unsigned short* __restrict__ p16,
                                              int N, int C) {
    __shared__ float Wl[40 * 65];
    __shared__ float xl[4][FDIM];

    for (int i = threadIdx.x; i < C * FDIM; i += 256) {
        int c = i >> 6, f = i & 63;
        Wl[c * 65 + f] = W[i];
    }
    int wave = threadIdx.x >> 6;
    int lane = threadIdx.x & 63;
    int node = blockIdx.x * 4 + wave;

    float xv = 0.0f;
    if (node < N) xv = x[(size_t)node * FDIM + lane];
    xl[wave][lane] = xv;
    __syncthreads();

    unsigned short r = 0;
    if (lane < C) {
        const float* wr = &Wl[lane * 65];
        const float* xr = xl[wave];
        float a = 0.0f;
#pragma unroll
        for (int f = 0; f < FDIM; ++f) a = fmaf(xr[f], wr[f], a);
        r = f2bf(a);
    }
    if (node < N) p16[(size_t)node * CPAD + lane] = r;  // pad lanes write 0
}

// ---------------- hop 1: gather in class space (bf16 rows, 128B/line) ------

__global__ __launch_bounds__(256) void k_hop1(const int* __restrict__ row_ptr,
                                              const int2* __restrict__ csr,
                                              const unsigned int* __restrict__ pin,
                                              unsigned int* __restrict__ yout,
                                              int N) {
    int wid = (blockIdx.x << 2) | (threadIdx.x >> 6);
    int lane = threadIdx.x & 63;
    int j = lane & 31;
    if (wid >= N) return;
    int beg = row_ptr[wid], end = row_ptr[wid + 1];

    float a0 = 0.0f, a1 = 0.0f;
    int e = beg + (lane >> 5);
    for (; e + 2 < end; e += 4) {
        int2 c0 = csr[e], c1 = csr[e + 2];
        float w0 = __int_as_float(c0.y), w1 = __int_as_float(c1.y);
        unsigned int v0 = pin[(size_t)c0.x * 32 + j];
        unsigned int v1 = pin[(size_t)c1.x * 32 + j];
        a0 = fmaf(w0, bf_lo(v0), a0); a1 = fmaf(w0, bf_hi(v0), a1);
        a0 = fmaf(w1, bf_lo(v1), a0); a1 = fmaf(w1, bf_hi(v1), a1);
    }
    if (e < end) {
        int2 c = csr[e];
        float w = __int_as_float(c.y);
        unsigned int v = pin[(size_t)c.x * 32 + j];
        a0 = fmaf(w, bf_lo(v), a0); a1 = fmaf(w, bf_hi(v), a1);
    }
    a0 += __shfl_xor(a0, 32);
    a1 += __shfl_xor(a1, 32);
    if (lane < 32) yout[(size_t)wid * 32 + j] = bfpack(a0, a1);
}

// ---------------- hop 2 fused with bias + log_softmax ----------------------

__global__ __launch_bounds__(256) void k_hop2_lsm(const int* __restrict__ row_ptr,
                                                  const int2* __restrict__ csr,
                                                  const unsigned int* __restrict__ pin,
                                                  const float* __restrict__ b,
                                                  float* __restrict__ out,
                                                  int N, int C) {
    int wid = (blockIdx.x << 2) | (threadIdx.x >> 6);
    int lane = threadIdx.x & 63;
    int j = lane & 31;
    if (wid >= N) return;
    int beg = row_ptr[wid], end = row_ptr[wid + 1];

    float a0 = 0.0f, a1 = 0.0f;
    int e = beg + (lane >> 5);
    for (; e + 2 < end; e += 4) {
        int2 c0 = csr[e], c1 = csr[e + 2];
        float w0 = __int_as_float(c0.y), w1 = __int_as_float(c1.y);
        unsigned int v0 = pin[(size_t)c0.x * 32 + j];
        unsigned int v1 = pin[(size_t)c1.x * 32 + j];
        a0 = fmaf(w0, bf_lo(v0), a0); a1 = fmaf(w0, bf_hi(v0), a1);
        a0 = fmaf(w1, bf_lo(v1), a0); a1 = fmaf(w1, bf_hi(v1), a1);
    }
    if (e < end) {
        int2 c = csr[e];
        float w = __int_as_float(c.y);
        unsigned int v = pin[(size_t)c.x * 32 + j];
        a0 = fmaf(w, bf_lo(v), a0); a1 = fmaf(w, bf_hi(v), a1);
    }
    a0 += __shfl_xor(a0, 32);
    a1 += __shfl_xor(a1, 32);

    int c0i = 2 * j;
    bool valid = (c0i < C);
    float l0 = -INFINITY, l1 = -INFINITY;
    if (valid) {
        l0 = a0 + b[c0i];
        l1 = a1 + b[c0i + 1];
    }
    float m = fmaxf(l0, l1);
#pragma unroll
    for (int o = 16; o > 0; o >>= 1) m = fmaxf(m, __shfl_xor(m, o));
    float s = valid ? (expf(l0 - m) + expf(l1 - m)) : 0.0f;
#pragma unroll
    for (int o = 16; o > 0; o >>= 1) s += __shfl_xor(s, o);
    float ls = logf(s);

    if (lane < 32 && valid) {
        float2 r = make_float2(l0 - m - ls, l1 - m - ls);
        *(float2*)&out[(size_t)wid * C + c0i] = r;
    }
}

// ---------------- launch ----------------

extern "C" void kernel_launch(void* const* d_in, const int* in_sizes, int n_in,
                              void* d_out, int out_size, void* d_ws, size_t ws_size,
                              hipStream_t stream) {
    const float* x  = (const float*)d_in[0];
    const int*   ei = (const int*)d_in[1];
    const float* W  = (const float*)d_in[2];
    const float* b  = (const float*)d_in[3];
    float* out = (float*)d_out;

    const int C = in_sizes[3];              // 40
    const int F = in_sizes[2] / C;          // 64
    const int N = in_sizes[0] / F;          // 100000
    const int E = in_sizes[1] / 2;          // 1200000
    (void)F;

    const int* src = ei;
    const int* dst = ei + E;
    const int T  = E + N;                   // CSR entries incl self-loops
    const int NB = (N + NPB - 1) / NPB;     // final buckets (391)
    const int NR = (N + (1 << RGSH) - 1) >> RGSH;  // regions (25)

    // ws layout, each segment 256B-aligned
    char* w8 = (char*)d_ws;
    auto alloc = [&](size_t bytes) {
        char* p = w8;
        w8 += (bytes + 255) & ~(size_t)255;
        return p;
    };
    int*   cursors = (int*)  alloc((size_t)(32 + NB) * 4);  // rcur[32] + bcnt[NB]
    int*   cbase   = (int*)  alloc((size_t)NB * 4);
    int*   row_ptr = (int*)  alloc((size_t)(N + 1) * 4);
    float* dinv    = (float*)alloc((size_t)N * 4);
    unsigned int* bin1 = (unsigned int*)alloc((size_t)NR * CAP1 * 4);  // 5.3 MB
    unsigned int* bin2 = (unsigned int*)alloc((size_t)NB * CAP2B * 4); // 5.4 MB
    int2*  csr     = (int2*) alloc((size_t)T * 8);                     // 10.4 MB
    unsigned short* p16 = (unsigned short*)alloc((size_t)N * CPAD * 2);
    unsigned int*   y16 = (unsigned int*)  alloc((size_t)N * 32 * 4);

    int* rcur = cursors;
    int* bcnt = cursors + 32;

    const int B = 256;
    const int NT1 = (E + TILE - 1) / TILE;  // 293 partition tiles

    k_zero   <<<(32 + NB + B - 1) / B, B, 0, stream>>>(cursors, 32 + NB);
    k_part1  <<<NT1, B, 0, stream>>>(src, dst, rcur, bin1, E, NR);
    k_part2  <<<dim3(8, NR), B, 0, stream>>>(rcur, bin1, bcnt, bin2);
    k_bscan  <<<1, 512, 0, stream>>>(bcnt, cbase, row_ptr, NB, N, T);
    k_build_a<<<NB, B, 0, stream>>>(bcnt, cbase, bin2, row_ptr, dinv, N);
    k_build_b<<<NB, B, 0, stream>>>(bcnt, bin2, row_ptr, dinv, csr, N);

    k_proj   <<<(N + 3) / 4, B, 0, stream>>>(x, W, p16, N, C);

    k_hop1   <<<(N + 3) / 4, B, 0, stream>>>(row_ptr, csr,
                                             (const unsigned int*)p16, y16, N);

    k_hop2_lsm<<<(N + 3) / 4, B, 0, stream>>>(row_ptr, csr, y16, b, out, N, C);
}

// Round 10
// 209.146 us; speedup vs baseline: 1.4622x; 1.4622x over previous
//
#include <hip/hip_runtime.h>
#include <math.h>

#define FDIM 64    // input feature dim
#define CPAD 64    // padded class dim (40 valid), bf16 -> 128B rows
#define NPB  256   // nodes per bucket (bucket = dst >> 8)
#define CAP2B 3456 // entries per bucket segment (mean 3069, +7 sigma)
#define NBMAX 400
#define TILE2 2048
#define EPT2 8     // TILE2 / 256

// ---------------- helpers ----------------

__device__ inline unsigned short f2bf(float f) {
    unsigned int u = __float_as_uint(f);
    unsigned int r = (u + 0x7fffu + ((u >> 16) & 1u)) >> 16;  // RNE
    return (unsigned short)r;
}
__device__ inline float bf_lo(unsigned int v) { return __uint_as_float(v << 16); }
__device__ inline float bf_hi(unsigned int v) { return __uint_as_float(v & 0xffff0000u); }
__device__ inline unsigned int bfpack(float a, float b) {
    return (unsigned int)f2bf(a) | ((unsigned int)f2bf(b) << 16);
}

__global__ __launch_bounds__(256) void k_zero(int* __restrict__ p, int n) {
    int i = blockIdx.x * 256 + threadIdx.x;
    if (i < n) p[i] = 0;
}

// ---------------- direct binning: edges -> 391 buckets, one pass -----------
// Per 2048-edge tile: LDS histogram over buckets, parallel global
// reservation (one atomicAdd per touched bucket), direct scattered writes
// of 4B packed entries (src<<8 | dst&255) into reserved windows.

__global__ __launch_bounds__(256) void k_binD(const int* __restrict__ src,
                                              const int* __restrict__ dst,
                                              int* __restrict__ bcnt,
                                              unsigned int* __restrict__ bin2,
                                              int E, int NB) {
    __shared__ int hb[NBMAX];   // histogram, then global base
    __shared__ int hc[NBMAX];   // rank cursor
    int tid = threadIdx.x;
    int base = blockIdx.x * TILE2;
    for (int i = tid; i < NB; i += 256) { hb[i] = 0; hc[i] = 0; }
    __syncthreads();
    unsigned int ent[EPT2]; int bk[EPT2];
#pragma unroll
    for (int k = 0; k < EPT2; ++k) {
        int i = base + k * 256 + tid;
        if (i < E) {
            int s = src[i], d = dst[i];
            bk[k] = d >> 8;
            ent[k] = ((unsigned int)s << 8) | (unsigned int)(d & 255);
            atomicAdd(&hb[bk[k]], 1);
        } else bk[k] = -1;
    }
    __syncthreads();
    for (int i = tid; i < NB; i += 256) {
        int c = hb[i];
        hb[i] = (c > 0) ? atomicAdd(&bcnt[i], c) : 0;
    }
    __syncthreads();
#pragma unroll
    for (int k = 0; k < EPT2; ++k) if (bk[k] >= 0) {
        int b = bk[k];
        int pos = hb[b] + atomicAdd(&hc[b], 1);
        if (pos < CAP2B) bin2[(size_t)b * CAP2B + pos] = ent[k];
    }
}

// ---------------- bucket-count scan -> CSR bases ----------------

__global__ __launch_bounds__(512) void k_bscan(const int* __restrict__ bcnt,
                                               int* __restrict__ cbase,
                                               int* __restrict__ row_ptr,
                                               int NB, int N, int T) {
    __shared__ int lds[512];
    int tid = threadIdx.x;
    int tot = 0;
    if (tid < NB)
        tot = min(bcnt[tid], CAP2B) + min(NPB, N - tid * NPB);  // + self entries
    lds[tid] = tot;
    __syncthreads();
    int val = tot;
#pragma unroll
    for (int off = 1; off < 512; off <<= 1) {
        int o = (tid >= off) ? lds[tid - off] : 0;
        __syncthreads();
        val += o;
        lds[tid] = val;
        __syncthreads();
    }
    if (tid < NB) cbase[tid] = val - tot;   // exclusive
    if (tid == 0) row_ptr[N] = T;
}

// per bucket: local histogram (init 1 = self) + scan -> row_ptr + dinv
__global__ __launch_bounds__(256) void k_build_a(const int* __restrict__ bcnt,
                                                 const int* __restrict__ cbase,
                                                 const unsigned int* __restrict__ bin2,
                                                 int* __restrict__ row_ptr,
                                                 float* __restrict__ dinv, int N) {
    __shared__ int lcnt[256];
    __shared__ int lscan[256];
    int b = blockIdx.x, tid = threadIdx.x;
    int node = (b << 8) + tid;
    lcnt[tid] = (node < N) ? 1 : 0;          // self entry
    __syncthreads();
    int M = min(bcnt[b], CAP2B);
    const unsigned int* seg = bin2 + (size_t)b * CAP2B;
    for (int i = tid; i < M; i += 256)
        atomicAdd(&lcnt[seg[i] & 255u], 1);
    __syncthreads();
    int v = lcnt[tid];
    lscan[tid] = v;
    __syncthreads();
    int val = v;
#pragma unroll
    for (int off = 1; off < 256; off <<= 1) {
        int o = (tid >= off) ? lscan[tid - off] : 0;
        __syncthreads();
        val += o;
        lscan[tid] = val;
        __syncthreads();
    }
    if (node < N) {
        row_ptr[node] = cbase[b] + (val - v);   // exclusive local offset
        dinv[node] = rsqrtf((float)v);          // count includes self entry
    }
}

// per bucket: scatter entries to final CSR slots ({src, w} packed int2)
__global__ __launch_bounds__(256) void k_build_b(const int* __restrict__ bcnt,
                                                 const unsigned int* __restrict__ bin2,
                                                 const int* __restrict__ row_ptr,
                                                 const float* __restrict__ dinv,
                                                 int2* __restrict__ csr, int N) {
    __shared__ int lbase[256];
    __shared__ int lcur[256];
    int b = blockIdx.x, tid = threadIdx.x;
    int node = (b << 8) + tid;
    if (node < N) {
        int base = row_ptr[node];
        lbase[tid] = base;
        float dn = dinv[node];
        csr[base] = make_int2(node, __float_as_int(dn * dn));  // self entry
    } else {
        lbase[tid] = 0;
    }
    lcur[tid] = 1;   // slot 0 taken by self
    __syncthreads();
    int M = min(bcnt[b], CAP2B);
    const unsigned int* seg = bin2 + (size_t)b * CAP2B;
    for (int i = tid; i < M; i += 256) {
        unsigned int en = seg[i];
        int s = (int)(en >> 8);
        int dl = (int)(en & 255u);
        int pos = lbase[dl] + atomicAdd(&lcur[dl], 1);
        float w = dinv[s] * dinv[(b << 8) + dl];
        csr[pos] = make_int2(s, __float_as_int(w));
    }
}

// ---------------- projection: p[n][c] = dot(x[n], W[c]), bf16-packed --------

__global__ __launch_bounds__(256) void k_proj(const float* __restrict__ x,
                                              const float* __restrict__ W,
                                              unsigned short* __restrict__ p16,
                                              int N, int C) {
    __shared__ float Wl[40 * 65];
    __shared__ float xl[4][FDIM];

    for (int i = threadIdx.x; i < C * FDIM; i += 256) {
        int c = i >> 6, f = i & 63;
        Wl[c * 65 + f] = W[i];
    }
    int wave = threadIdx.x >> 6;
    int lane = threadIdx.x & 63;
    int node = blockIdx.x * 4 + wave;

    float xv = 0.0f;
    if (node < N) xv = x[(size_t)node * FDIM + lane];
    xl[wave][lane] = xv;
    __syncthreads();

    unsigned short r = 0;
    if (lane < C) {
        const float* wr = &Wl[lane * 65];
        const float* xr = xl[wave];
        float a = 0.0f;
#pragma unroll
        for (int f = 0; f < FDIM; ++f) a = fmaf(xr[f], wr[f], a);
        r = f2bf(a);
    }
    if (node < N) p16[(size_t)node * CPAD + lane] = r;  // pad lanes write 0
}

// ---------------- hop 1: gather in class space (bf16 rows, 128B/line) ------

__global__ __launch_bounds__(256) void k_hop1(const int* __restrict__ row_ptr,
                                              const int2* __restrict__ csr,
                                              const unsigned int* __restrict__ pin,
                                              unsigned int* __restrict__ yout,
                                              int N) {
    int wid = (blockIdx.x << 2) | (threadIdx.x >> 6);
    int lane = threadIdx.x & 63;
    int j = lane & 31;
    if (wid >= N) return;
    int beg = row_ptr[wid], end = row_ptr[wid + 1];

    float a0 = 0.0f, a1 = 0.0f;
    int e = beg + (lane >> 5);
    for (; e + 2 < end; e += 4) {
        int2 c0 = csr[e], c1 = csr[e + 2];
        float w0 = __int_as_float(c0.y), w1 = __int_as_float(c1.y);
        unsigned int v0 = pin[(size_t)c0.x * 32 + j];
        unsigned int v1 = pin[(size_t)c1.x * 32 + j];
        a0 = fmaf(w0, bf_lo(v0), a0); a1 = fmaf(w0, bf_hi(v0), a1);
        a0 = fmaf(w1, bf_lo(v1), a0); a1 = fmaf(w1, bf_hi(v1), a1);
    }
    if (e < end) {
        int2 c = csr[e];
        float w = __int_as_float(c.y);
        unsigned int v = pin[(size_t)c.x * 32 + j];
        a0 = fmaf(w, bf_lo(v), a0); a1 = fmaf(w, bf_hi(v), a1);
    }
    a0 += __shfl_xor(a0, 32);
    a1 += __shfl_xor(a1, 32);
    if (lane < 32) yout[(size_t)wid * 32 + j] = bfpack(a0, a1);
}

// ---------------- hop 2 fused with bias + log_softmax ----------------------

__global__ __launch_bounds__(256) void k_hop2_lsm(const int* __restrict__ row_ptr,
                                                  const int2* __restrict__ csr,
                                                  const unsigned int* __restrict__ pin,
                                                  const float* __restrict__ b,
                                                  float* __restrict__ out,
                                                  int N, int C) {
    int wid = (blockIdx.x << 2) | (threadIdx.x >> 6);
    int lane = threadIdx.x & 63;
    int j = lane & 31;
    if (wid >= N) return;
    int beg = row_ptr[wid], end = row_ptr[wid + 1];

    float a0 = 0.0f, a1 = 0.0f;
    int e = beg + (lane >> 5);
    for (; e + 2 < end; e += 4) {
        int2 c0 = csr[e], c1 = csr[e + 2];
        float w0 = __int_as_float(c0.y), w1 = __int_as_float(c1.y);
        unsigned int v0 = pin[(size_t)c0.x * 32 + j];
        unsigned int v1 = pin[(size_t)c1.x * 32 + j];
        a0 = fmaf(w0, bf_lo(v0), a0); a1 = fmaf(w0, bf_hi(v0), a1);
        a0 = fmaf(w1, bf_lo(v1), a0); a1 = fmaf(w1, bf_hi(v1), a1);
    }
    if (e < end) {
        int2 c = csr[e];
        float w = __int_as_float(c.y);
        unsigned int v = pin[(size_t)c.x * 32 + j];
        a0 = fmaf(w, bf_lo(v), a0); a1 = fmaf(w, bf_hi(v), a1);
    }
    a0 += __shfl_xor(a0, 32);
    a1 += __shfl_xor(a1, 32);

    int c0i = 2 * j;
    bool valid = (c0i < C);
    float l0 = -INFINITY, l1 = -INFINITY;
    if (valid) {
        l0 = a0 + b[c0i];
        l1 = a1 + b[c0i + 1];
    }
    float m = fmaxf(l0, l1);
#pragma unroll
    for (int o = 16; o > 0; o >>= 1) m = fmaxf(m, __shfl_xor(m, o));
    float s = valid ? (expf(l0 - m) + expf(l1 - m)) : 0.0f;
#pragma unroll
    for (int o = 16; o > 0; o >>= 1) s += __shfl_xor(s, o);
    float ls = logf(s);

    if (lane < 32 && valid) {
        float2 r = make_float2(l0 - m - ls, l1 - m - ls);
        *(float2*)&out[(size_t)wid * C + c0i] = r;
    }
}

// ---------------- launch ----------------

extern "C" void kernel_launch(void* const* d_in, const int* in_sizes, int n_in,
                              void* d_out, int out_size, void* d_ws, size_t ws_size,
                              hipStream_t stream) {
    const float* x  = (const float*)d_in[0];
    const int*   ei = (const int*)d_in[1];
    const float* W  = (const float*)d_in[2];
    const float* b  = (const float*)d_in[3];
    float* out = (float*)d_out;

    const int C = in_sizes[3];              // 40
    const int F = in_sizes[2] / C;          // 64
    const int N = in_sizes[0] / F;          // 100000
    const int E = in_sizes[1] / 2;          // 1200000
    (void)F;

    const int* src = ei;
    const int* dst = ei + E;
    const int T  = E + N;                   // CSR entries incl self-loops
    const int NB = (N + NPB - 1) / NPB;     // buckets (391)

    // ws layout, each segment 256B-aligned
    char* w8 = (char*)d_ws;
    auto alloc = [&](size_t bytes) {
        char* p = w8;
        w8 += (bytes + 255) & ~(size_t)255;
        return p;
    };
    int*   bcnt    = (int*)  alloc((size_t)NB * 4);
    int*   cbase   = (int*)  alloc((size_t)NB * 4);
    int*   row_ptr = (int*)  alloc((size_t)(N + 1) * 4);
    float* dinv    = (float*)alloc((size_t)N * 4);
    unsigned int* bin2 = (unsigned int*)alloc((size_t)NB * CAP2B * 4); // 5.4 MB
    int2*  csr     = (int2*) alloc((size_t)T * 8);                     // 10.4 MB
    unsigned short* p16 = (unsigned short*)alloc((size_t)N * CPAD * 2);
    unsigned int*   y16 = (unsigned int*)  alloc((size_t)N * 32 * 4);

    const int B = 256;
    const int NT = (E + TILE2 - 1) / TILE2;  // 586 binning tiles

    k_zero   <<<(NB + B - 1) / B, B, 0, stream>>>(bcnt, NB);
    k_binD   <<<NT, B, 0, stream>>>(src, dst, bcnt, bin2, E, NB);
    k_bscan  <<<1, 512, 0, stream>>>(bcnt, cbase, row_ptr, NB, N, T);
    k_build_a<<<NB, B, 0, stream>>>(bcnt, cbase, bin2, row_ptr, dinv, N);
    k_build_b<<<NB, B, 0, stream>>>(bcnt, bin2, row_ptr, dinv, csr, N);

    k_proj   <<<(N + 3) / 4, B, 0, stream>>>(x, W, p16, N, C);

    k_hop1   <<<(N + 3) / 4, B, 0, stream>>>(row_ptr, csr,
                                             (const unsigned int*)p16, y16, N);

    k_hop2_lsm<<<(N + 3) / 4, B, 0, stream>>>(row_ptr, csr, y16, b, out, N, C);
}

// Round 14
// 175.264 us; speedup vs baseline: 1.7449x; 1.1933x over previous
//
#include <hip/hip_runtime.h>
#include <math.h>

#define FDIM 64    // input feature dim
#define CPAD 64    // padded class dim (40 valid), bf16 -> 128B rows
#define NPB  256   // nodes per bucket (bucket = dst >> 8)
#define CAP2B 3456 // entries per bucket segment (mean 3069, +7 sigma)
#define NBMAX 400
#define TILE2 2048
#define EPT2 8     // TILE2 / 256

// ---------------- helpers ----------------

__device__ inline unsigned short f2bf(float f) {
    unsigned int u = __float_as_uint(f);
    unsigned int r = (u + 0x7fffu + ((u >> 16) & 1u)) >> 16;  // RNE
    return (unsigned short)r;
}
__device__ inline float bf_lo(unsigned int v) { return __uint_as_float(v << 16); }
__device__ inline float bf_hi(unsigned int v) { return __uint_as_float(v & 0xffff0000u); }
__device__ inline unsigned int bfpack(float a, float b) {
    return (unsigned int)f2bf(a) | ((unsigned int)f2bf(b) << 16);
}

__global__ __launch_bounds__(256) void k_zero(int* __restrict__ p, int n) {
    int i = blockIdx.x * 256 + threadIdx.x;
    if (i < n) p[i] = 0;
}

// ---------------- direct binning: edges -> 391 buckets, one pass -----------
// Per 2048-edge tile: LDS histogram over buckets, parallel global
// reservation (one atomicAdd per touched bucket), direct scattered writes
// of 4B packed entries (src<<8 | dst&255) into reserved windows.

__global__ __launch_bounds__(256) void k_binD(const int* __restrict__ src,
                                              const int* __restrict__ dst,
                                              int* __restrict__ bcnt,
                                              unsigned int* __restrict__ bin2,
                                              int E, int NB) {
    __shared__ int hb[NBMAX];   // histogram, then global base
    __shared__ int hc[NBMAX];   // rank cursor
    int tid = threadIdx.x;
    int base = blockIdx.x * TILE2;
    for (int i = tid; i < NB; i += 256) { hb[i] = 0; hc[i] = 0; }
    __syncthreads();
    unsigned int ent[EPT2]; int bk[EPT2];
#pragma unroll
    for (int k = 0; k < EPT2; ++k) {
        int i = base + k * 256 + tid;
        if (i < E) {
            int s = src[i], d = dst[i];
            bk[k] = d >> 8;
            ent[k] = ((unsigned int)s << 8) | (unsigned int)(d & 255);
            atomicAdd(&hb[bk[k]], 1);
        } else bk[k] = -1;
    }
    __syncthreads();
    for (int i = tid; i < NB; i += 256) {
        int c = hb[i];
        hb[i] = (c > 0) ? atomicAdd(&bcnt[i], c) : 0;
    }
    __syncthreads();
#pragma unroll
    for (int k = 0; k < EPT2; ++k) if (bk[k] >= 0) {
        int b = bk[k];
        int pos = hb[b] + atomicAdd(&hc[b], 1);
        if (pos < CAP2B) bin2[(size_t)b * CAP2B + pos] = ent[k];
    }
}

// ---------------- bucket-count scan -> CSR bases ----------------

__global__ __launch_bounds__(512) void k_bscan(const int* __restrict__ bcnt,
                                               int* __restrict__ cbase,
                                               int* __restrict__ row_ptr,
                                               int NB, int N, int T) {
    __shared__ int lds[512];
    int tid = threadIdx.x;
    int tot = 0;
    if (tid < NB)
        tot = min(bcnt[tid], CAP2B) + min(NPB, N - tid * NPB);  // + self entries
    lds[tid] = tot;
    __syncthreads();
    int val = tot;
#pragma unroll
    for (int off = 1; off < 512; off <<= 1) {
        int o = (tid >= off) ? lds[tid - off] : 0;
        __syncthreads();
        val += o;
        lds[tid] = val;
        __syncthreads();
    }
    if (tid < NB) cbase[tid] = val - tot;   // exclusive
    if (tid == 0) row_ptr[N] = T;
}

// per bucket: histogram (init 1 = self) + scan -> row_ptr/dinv, then scatter
// src-only CSR entries (weights folded into node scaling; see k_proj/hops)
__global__ __launch_bounds__(256) void k_build(const int* __restrict__ bcnt,
                                               const int* __restrict__ cbase,
                                               const unsigned int* __restrict__ bin2,
                                               int* __restrict__ row_ptr,
                                               float* __restrict__ dinv,
                                               int* __restrict__ csr_src, int N) {
    __shared__ int lcnt[256];
    __shared__ int lscan[256];
    __shared__ int lbase[256];
    __shared__ int lcur[256];
    int b = blockIdx.x, tid = threadIdx.x;
    int node = (b << 8) + tid;
    lcnt[tid] = (node < N) ? 1 : 0;          // self entry
    __syncthreads();
    int M = min(bcnt[b], CAP2B);
    const unsigned int* seg = bin2 + (size_t)b * CAP2B;
    for (int i = tid; i < M; i += 256)
        atomicAdd(&lcnt[seg[i] & 255u], 1);
    __syncthreads();
    int v = lcnt[tid];
    lscan[tid] = v;
    __syncthreads();
    int val = v;
#pragma unroll
    for (int off = 1; off < 256; off <<= 1) {
        int o = (tid >= off) ? lscan[tid - off] : 0;
        __syncthreads();
        val += o;
        lscan[tid] = val;
        __syncthreads();
    }
    int base = cbase[b] + (val - v);         // exclusive local offset
    if (node < N) {
        row_ptr[node] = base;
        dinv[node] = rsqrtf((float)v);       // count includes self entry
        csr_src[base] = node;                // self entry at slot 0
    }
    lbase[tid] = base;
    lcur[tid] = 1;                           // slot 0 taken by self
    __syncthreads();
    for (int i = tid; i < M; i += 256) {
        unsigned int en = seg[i];
        int dl = (int)(en & 255u);
        int pos = lbase[dl] + atomicAdd(&lcur[dl], 1);
        csr_src[pos] = (int)(en >> 8);
    }
}

// ---------------- projection: p''[n][c] = dinv[n]*dot(x[n], W[c]) ----------

__global__ __launch_bounds__(256) void k_proj(const float* __restrict__ x,
                                              const float* __restrict__ W,
                                              const float* __restrict__ dinv,
                                              unsigned short* __restrict__ p16,
                                              int N, int C) {
    __shared__ float Wl[40 * 65];
    __shared__ float xl[4][FDIM];

    for (int i = threadIdx.x; i < C * FDIM; i += 256) {
        int c = i >> 6, f = i & 63;
        Wl[c * 65 + f] = W[i];
    }
    int wave = threadIdx.x >> 6;
    int lane = threadIdx.x & 63;
    int node = blockIdx.x * 4 + wave;

    float xv = 0.0f, dn = 0.0f;
    if (node < N) {
        xv = x[(size_t)node * FDIM + lane];
        dn = dinv[node];
    }
    xl[wave][lane] = xv;
    __syncthreads();

    unsigned short r = 0;
    if (lane < C) {
        const float* wr = &Wl[lane * 65];
        const float* xr = xl[wave];
        float a = 0.0f;
#pragma unroll
        for (int f = 0; f < FDIM; ++f) a = fmaf(xr[f], wr[f], a);
        r = f2bf(a * dn);
    }
    if (node < N) p16[(size_t)node * CPAD + lane] = r;  // pad lanes write 0
}

// ---------------- hop 1: unweighted gather-sum, rescale by dinv^2 ----------
// wave per node; halves take even/odd CSR entries; 8-deep gather batches

__global__ __launch_bounds__(256) void k_hop1(const int* __restrict__ row_ptr,
                                              const int* __restrict__ csr_src,
                                              const float* __restrict__ dinv,
                                              const unsigned int* __restrict__ pin,
                                              unsigned int* __restrict__ yout,
                                              int N) {
    int wid = (blockIdx.x << 2) | (threadIdx.x >> 6);
    int lane = threadIdx.x & 63;
    int j = lane & 31, half = lane >> 5;
    if (wid >= N) return;
    int beg = row_ptr[wid], end = row_ptr[wid + 1];

    float a0 = 0.0f, a1 = 0.0f;
    for (int e0 = beg + half; e0 < end; e0 += 16) {
        int si[8]; unsigned int vs[8];
#pragma unroll
        for (int k = 0; k < 8; ++k) {
            int idx = e0 + 2 * k;
            si[k] = (idx < end) ? csr_src[idx] : -1;
        }
#pragma unroll
        for (int k = 0; k < 8; ++k)
            if (si[k] >= 0) vs[k] = pin[(size_t)si[k] * 32 + j];
#pragma unroll
        for (int k = 0; k < 8; ++k)
            if (si[k] >= 0) { a0 += bf_lo(vs[k]); a1 += bf_hi(vs[k]); }
    }
    a0 += __shfl_xor(a0, 32);
    a1 += __shfl_xor(a1, 32);
    if (lane < 32) {
        float dn = dinv[wid];
        float sc = dn * dn;
        yout[(size_t)wid * 32 + j] = bfpack(a0 * sc, a1 * sc);
    }
}

// ---------------- hop 2 fused with bias + log_softmax ----------------------

__global__ __launch_bounds__(256) void k_hop2_lsm(const int* __restrict__ row_ptr,
                                                  const int* __restrict__ csr_src,
                                                  const float* __restrict__ dinv,
                                                  const unsigned int* __restrict__ pin,
                                                  const float* __restrict__ b,
                                                  float* __restrict__ out,
                                                  int N, int C) {
    int wid = (blockIdx.x << 2) | (threadIdx.x >> 6);
    int lane = threadIdx.x & 63;
    int j = lane & 31, half = lane >> 5;
    if (wid >= N) return;
    int beg = row_ptr[wid], end = row_ptr[wid + 1];

    float a0 = 0.0f, a1 = 0.0f;
    for (int e0 = beg + half; e0 < end; e0 += 16) {
        int si[8]; unsigned int vs[8];
#pragma unroll
        for (int k = 0; k < 8; ++k) {
            int idx = e0 + 2 * k;
            si[k] = (idx < end) ? csr_src[idx] : -1;
        }
#pragma unroll
        for (int k = 0; k < 8; ++k)
            if (si[k] >= 0) vs[k] = pin[(size_t)si[k] * 32 + j];
#pragma unroll
        for (int k = 0; k < 8; ++k)
            if (si[k] >= 0) { a0 += bf_lo(vs[k]); a1 += bf_hi(vs[k]); }
    }
    a0 += __shfl_xor(a0, 32);
    a1 += __shfl_xor(a1, 32);

    float dn = dinv[wid];
    int c0i = 2 * j;
    bool valid = (c0i < C);
    float l0 = -INFINITY, l1 = -INFINITY;
    if (valid) {
        l0 = a0 * dn + b[c0i];
        l1 = a1 * dn + b[c0i + 1];
    }
    float m = fmaxf(l0, l1);
#pragma unroll
    for (int o = 16; o > 0; o >>= 1) m = fmaxf(m, __shfl_xor(m, o));
    float s = valid ? (expf(l0 - m) + expf(l1 - m)) : 0.0f;
#pragma unroll
    for (int o = 16; o > 0; o >>= 1) s += __shfl_xor(s, o);
    float ls = logf(s);

    if (lane < 32 && valid) {
        float2 r = make_float2(l0 - m - ls, l1 - m - ls);
        *(float2*)&out[(size_t)wid * C + c0i] = r;
    }
}

// ---------------- launch ----------------

extern "C" void kernel_launch(void* const* d_in, const int* in_sizes, int n_in,
                              void* d_out, int out_size, void* d_ws, size_t ws_size,
                              hipStream_t stream) {
    const float* x  = (const float*)d_in[0];
    const int*   ei = (const int*)d_in[1];
    const float* W  = (const float*)d_in[2];
    const float* b  = (const float*)d_in[3];
    float* out = (float*)d_out;

    const int C = in_sizes[3];              // 40
    const int F = in_sizes[2] / C;          // 64
    const int N = in_sizes[0] / F;          // 100000
    const int E = in_sizes[1] / 2;          // 1200000
    (void)F;

    const int* src = ei;
    const int* dst = ei + E;
    const int T  = E + N;                   // CSR entries incl self-loops
    const int NB = (N + NPB - 1) / NPB;     // buckets (391)

    // ws layout, each segment 256B-aligned
    char* w8 = (char*)d_ws;
    auto alloc = [&](size_t bytes) {
        char* p = w8;
        w8 += (bytes + 255) & ~(size_t)255;
        return p;
    };
    int*   bcnt    = (int*)  alloc((size_t)NB * 4);
    int*   cbase   = (int*)  alloc((size_t)NB * 4);
    int*   row_ptr = (int*)  alloc((size_t)(N + 1) * 4);
    float* dinv    = (float*)alloc((size_t)N * 4);
    unsigned int* bin2 = (unsigned int*)alloc((size_t)NB * CAP2B * 4); // 5.4 MB
    int*   csr_src = (int*)  alloc((size_t)T * 4);                     // 5.2 MB
    unsigned short* p16 = (unsigned short*)alloc((size_t)N * CPAD * 2);
    unsigned int*   y16 = (unsigned int*)  alloc((size_t)N * 32 * 4);

    const int B = 256;
    const int NT = (E + TILE2 - 1) / TILE2;  // 586 binning tiles

    k_zero <<<(NB + B - 1) / B, B, 0, stream>>>(bcnt, NB);
    k_binD <<<NT, B, 0, stream>>>(src, dst, bcnt, bin2, E, NB);
    k_bscan<<<1, 512, 0, stream>>>(bcnt, cbase, row_ptr, NB, N, T);
    k_build<<<NB, B, 0, stream>>>(bcnt, cbase, bin2, row_ptr, dinv, csr_src, N);

    k_proj <<<(N + 3) / 4, B, 0, stream>>>(x, W, dinv, p16, N, C);

    k_hop1 <<<(N + 3) / 4, B, 0, stream>>>(row_ptr, csr_src, dinv,
                                           (const unsigned int*)p16, y16, N);

    k_hop2_lsm<<<(N + 3) / 4, B, 0, stream>>>(row_ptr, csr_src, dinv,
                                              y16, b, out, N, C);
}

// Round 15
// 156.322 us; speedup vs baseline: 1.9563x; 1.1212x over previous
//
#include <hip/hip_runtime.h>
#include <math.h>

#define FDIM 64    // input feature dim
#define CPAD 64    // padded class dim (40 valid), bf16 -> 128B rows
#define NPB  256   // nodes per bucket (bucket = dst >> 8)
#define CAP2B 3456 // entries per bucket segment (mean 3069, +7 sigma)
#define NBMAX 400
#define TILE2 2048
#define EPT2 8     // TILE2 / 256
#define PTILE 128  // nodes per k_proj block

// ---------------- helpers ----------------

__device__ inline unsigned short f2bf(float f) {
    unsigned int u = __float_as_uint(f);
    unsigned int r = (u + 0x7fffu + ((u >> 16) & 1u)) >> 16;  // RNE
    return (unsigned short)r;
}
__device__ inline float bf_lo(unsigned int v) { return __uint_as_float(v << 16); }
__device__ inline float bf_hi(unsigned int v) { return __uint_as_float(v & 0xffff0000u); }
__device__ inline unsigned int bfpack(float a, float b) {
    return (unsigned int)f2bf(a) | ((unsigned int)f2bf(b) << 16);
}

__global__ __launch_bounds__(256) void k_zero(int* __restrict__ p, int n) {
    int i = blockIdx.x * 256 + threadIdx.x;
    if (i < n) p[i] = 0;
}

// ---------------- direct binning: edges -> 391 buckets, one pass -----------

__global__ __launch_bounds__(256) void k_binD(const int* __restrict__ src,
                                              const int* __restrict__ dst,
                                              int* __restrict__ bcnt,
                                              unsigned int* __restrict__ bin2,
                                              int E, int NB) {
    __shared__ int hb[NBMAX];   // histogram, then global base
    __shared__ int hc[NBMAX];   // rank cursor
    int tid = threadIdx.x;
    int base = blockIdx.x * TILE2;
    for (int i = tid; i < NB; i += 256) { hb[i] = 0; hc[i] = 0; }
    __syncthreads();
    unsigned int ent[EPT2]; int bk[EPT2];
#pragma unroll
    for (int k = 0; k < EPT2; ++k) {
        int i = base + k * 256 + tid;
        if (i < E) {
            int s = src[i], d = dst[i];
            bk[k] = d >> 8;
            ent[k] = ((unsigned int)s << 8) | (unsigned int)(d & 255);
            atomicAdd(&hb[bk[k]], 1);
        } else bk[k] = -1;
    }
    __syncthreads();
    for (int i = tid; i < NB; i += 256) {
        int c = hb[i];
        hb[i] = (c > 0) ? atomicAdd(&bcnt[i], c) : 0;
    }
    __syncthreads();
#pragma unroll
    for (int k = 0; k < EPT2; ++k) if (bk[k] >= 0) {
        int b = bk[k];
        int pos = hb[b] + atomicAdd(&hc[b], 1);
        if (pos < CAP2B) bin2[(size_t)b * CAP2B + pos] = ent[k];
    }
}

// ---------------- bucket-count scan -> CSR bases ----------------

__global__ __launch_bounds__(512) void k_bscan(const int* __restrict__ bcnt,
                                               int* __restrict__ cbase,
                                               int* __restrict__ row_ptr,
                                               int NB, int N, int T) {
    __shared__ int lds[512];
    int tid = threadIdx.x;
    int tot = 0;
    if (tid < NB)
        tot = min(bcnt[tid], CAP2B) + min(NPB, N - tid * NPB);  // + self entries
    lds[tid] = tot;
    __syncthreads();
    int val = tot;
#pragma unroll
    for (int off = 1; off < 512; off <<= 1) {
        int o = (tid >= off) ? lds[tid - off] : 0;
        __syncthreads();
        val += o;
        lds[tid] = val;
        __syncthreads();
    }
    if (tid < NB) cbase[tid] = val - tot;   // exclusive
    if (tid == 0) row_ptr[N] = T;
}

// per bucket: histogram (init 1 = self) + scan -> row_ptr/dinv, then scatter
// src-only CSR entries (weights folded into node scaling; see k_proj/hops)
__global__ __launch_bounds__(256) void k_build(const int* __restrict__ bcnt,
                                               const int* __restrict__ cbase,
                                               const unsigned int* __restrict__ bin2,
                                               int* __restrict__ row_ptr,
                                               float* __restrict__ dinv,
                                               int* __restrict__ csr_src, int N) {
    __shared__ int lcnt[256];
    __shared__ int lscan[256];
    __shared__ int lbase[256];
    __shared__ int lcur[256];
    int b = blockIdx.x, tid = threadIdx.x;
    int node = (b << 8) + tid;
    lcnt[tid] = (node < N) ? 1 : 0;          // self entry
    __syncthreads();
    int M = min(bcnt[b], CAP2B);
    const unsigned int* seg = bin2 + (size_t)b * CAP2B;
    for (int i = tid; i < M; i += 256)
        atomicAdd(&lcnt[seg[i] & 255u], 1);
    __syncthreads();
    int v = lcnt[tid];
    lscan[tid] = v;
    __syncthreads();
    int val = v;
#pragma unroll
    for (int off = 1; off < 256; off <<= 1) {
        int o = (tid >= off) ? lscan[tid - off] : 0;
        __syncthreads();
        val += o;
        lscan[tid] = val;
        __syncthreads();
    }
    int base = cbase[b] + (val - v);         // exclusive local offset
    if (node < N) {
        row_ptr[node] = base;
        dinv[node] = rsqrtf((float)v);       // count includes self entry
        csr_src[base] = node;                // self entry at slot 0
    }
    lbase[tid] = base;
    lcur[tid] = 1;                           // slot 0 taken by self
    __syncthreads();
    for (int i = tid; i < M; i += 256) {
        unsigned int en = seg[i];
        int dl = (int)(en & 255u);
        int pos = lbase[dl] + atomicAdd(&lcur[dl], 1);
        csr_src[pos] = (int)(en >> 8);
    }
}

// ---------------- projection: p''[n][c] = dinv[n]*dot(x[n], W[c]) ----------
// register-blocked tiled GEMM: 128-node tile, 4 nodes x 5 classes / thread

__global__ __launch_bounds__(256) void k_proj(const float* __restrict__ x,
                                              const float* __restrict__ W,
                                              const float* __restrict__ dinv,
                                              unsigned short* __restrict__ p16,
                                              int N, int C) {
    __shared__ float xs[PTILE][65];   // dinv-scaled x rows (pitch 65: no conflicts)
    __shared__ float Wl[40 * 65];
    int tid = threadIdx.x;
    int n0 = blockIdx.x * PTILE;

    for (int i = tid; i < 40 * 64; i += 256) {
        int c = i >> 6, f = i & 63;
        Wl[c * 65 + f] = W[i];
    }
    // stage x * dinv (float4 loads, 8 per thread)
    for (int idx = tid; idx < PTILE * 16; idx += 256) {
        int r = idx >> 4, c4 = (idx & 15) << 2;
        int n = n0 + r;
        float4 v = make_float4(0.f, 0.f, 0.f, 0.f);
        float dn = 0.f;
        if (n < N) {
            v = *(const float4*)&x[(size_t)n * FDIM + c4];
            dn = dinv[n];
        }
        xs[r][c4 + 0] = v.x * dn; xs[r][c4 + 1] = v.y * dn;
        xs[r][c4 + 2] = v.z * dn; xs[r][c4 + 3] = v.w * dn;
    }
    __syncthreads();

    int ng = tid & 31;   // node lane: rows ng, ng+32, ng+64, ng+96
    int cg = tid >> 5;   // class group 0..7: classes cg*5 .. cg*5+4
    float acc[4][5];
#pragma unroll
    for (int i = 0; i < 4; ++i)
#pragma unroll
        for (int j = 0; j < 5; ++j) acc[i][j] = 0.f;

#pragma unroll 4
    for (int k = 0; k < FDIM; ++k) {
        float xv[4], wv[5];
#pragma unroll
        for (int i = 0; i < 4; ++i) xv[i] = xs[ng + 32 * i][k];
#pragma unroll
        for (int j = 0; j < 5; ++j) wv[j] = Wl[(cg * 5 + j) * 65 + k];
#pragma unroll
        for (int i = 0; i < 4; ++i)
#pragma unroll
            for (int j = 0; j < 5; ++j)
                acc[i][j] = fmaf(xv[i], wv[j], acc[i][j]);
    }
    __syncthreads();

    // pack bf16 into LDS (reuse xs), zero pad cols, coalesced copy out
    unsigned short* ps = (unsigned short*)xs;    // [PTILE][64] u16 = 16 KB
#pragma unroll
    for (int i = 0; i < 4; ++i) {
        int r = ng + 32 * i;
#pragma unroll
        for (int j = 0; j < 5; ++j)
            ps[r * 64 + cg * 5 + j] = f2bf(acc[i][j]);
    }
    for (int idx = tid; idx < PTILE * 24; idx += 256) {
        int r = idx / 24, c = 40 + idx % 24;
        ps[r * 64 + c] = 0;
    }
    __syncthreads();
    const unsigned int* pu = (const unsigned int*)ps;
    unsigned int* po = (unsigned int*)p16;
    for (int idx = tid; idx < PTILE * 32; idx += 256) {
        int r = idx >> 5;
        int n = n0 + r;
        if (n < N) po[(size_t)n * 32 + (idx & 31)] = pu[idx];
    }
}

// ---------------- hop 1: unweighted gather-sum, rescale by dinv^2 ----------
// wave per node; halves take even/odd CSR entries; 8-deep gather batches

__global__ __launch_bounds__(256) void k_hop1(const int* __restrict__ row_ptr,
                                              const int* __restrict__ csr_src,
                                              const float* __restrict__ dinv,
                                              const unsigned int* __restrict__ pin,
                                              unsigned int* __restrict__ yout,
                                              int N) {
    int wid = (blockIdx.x << 2) | (threadIdx.x >> 6);
    int lane = threadIdx.x & 63;
    int j = lane & 31, half = lane >> 5;
    if (wid >= N) return;
    int beg = row_ptr[wid], end = row_ptr[wid + 1];

    float a0 = 0.0f, a1 = 0.0f;
    for (int e0 = beg + half; e0 < end; e0 += 16) {
        int si[8]; unsigned int vs[8];
#pragma unroll
        for (int k = 0; k < 8; ++k) {
            int idx = e0 + 2 * k;
            si[k] = (idx < end) ? csr_src[idx] : -1;
        }
#pragma unroll
        for (int k = 0; k < 8; ++k)
            if (si[k] >= 0) vs[k] = pin[(size_t)si[k] * 32 + j];
#pragma unroll
        for (int k = 0; k < 8; ++k)
            if (si[k] >= 0) { a0 += bf_lo(vs[k]); a1 += bf_hi(vs[k]); }
    }
    a0 += __shfl_xor(a0, 32);
    a1 += __shfl_xor(a1, 32);
    if (lane < 32) {
        float dn = dinv[wid];
        float sc = dn * dn;
        yout[(size_t)wid * 32 + j] = bfpack(a0 * sc, a1 * sc);
    }
}

// ---------------- hop 2 fused with bias + log_softmax ----------------------

__global__ __launch_bounds__(256) void k_hop2_lsm(const int* __restrict__ row_ptr,
                                                  const int* __restrict__ csr_src,
                                                  const float* __restrict__ dinv,
                                                  const unsigned int* __restrict__ pin,
                                                  const float* __restrict__ b,
                                                  float* __restrict__ out,
                                                  int N, int C) {
    int wid = (blockIdx.x << 2) | (threadIdx.x >> 6);
    int lane = threadIdx.x & 63;
    int j = lane & 31, half = lane >> 5;
    if (wid >= N) return;
    int beg = row_ptr[wid], end = row_ptr[wid + 1];

    float a0 = 0.0f, a1 = 0.0f;
    for (int e0 = beg + half; e0 < end; e0 += 16) {
        int si[8]; unsigned int vs[8];
#pragma unroll
        for (int k = 0; k < 8; ++k) {
            int idx = e0 + 2 * k;
            si[k] = (idx < end) ? csr_src[idx] : -1;
        }
#pragma unroll
        for (int k = 0; k < 8; ++k)
            if (si[k] >= 0) vs[k] = pin[(size_t)si[k] * 32 + j];
#pragma unroll
        for (int k = 0; k < 8; ++k)
            if (si[k] >= 0) { a0 += bf_lo(vs[k]); a1 += bf_hi(vs[k]); }
    }
    a0 += __shfl_xor(a0, 32);
    a1 += __shfl_xor(a1, 32);

    float dn = dinv[wid];
    int c0i = 2 * j;
    bool valid = (c0i < C);
    float l0 = -INFINITY, l1 = -INFINITY;
    if (valid) {
        l0 = a0 * dn + b[c0i];
        l1 = a1 * dn + b[c0i + 1];
    }
    float m = fmaxf(l0, l1);
#pragma unroll
    for (int o = 16; o > 0; o >>= 1) m = fmaxf(m, __shfl_xor(m, o));
    float s = valid ? (expf(l0 - m) + expf(l1 - m)) : 0.0f;
#pragma unroll
    for (int o = 16; o > 0; o >>= 1) s += __shfl_xor(s, o);
    float ls = logf(s);

    if (lane < 32 && valid) {
        float2 r = make_float2(l0 - m - ls, l1 - m - ls);
        *(float2*)&out[(size_t)wid * C + c0i] = r;
    }
}

// ---------------- launch ----------------

extern "C" void kernel_launch(void* const* d_in, const int* in_sizes, int n_in,
                              void* d_out, int out_size, void* d_ws, size_t ws_size,
                              hipStream_t stream) {
    const float* x  = (const float*)d_in[0];
    const int*   ei = (const int*)d_in[1];
    const float* W  = (const float*)d_in[2];
    const float* b  = (const float*)d_in[3];
    float* out = (float*)d_out;

    const int C = in_sizes[3];              // 40
    const int F = in_sizes[2] / C;          // 64
    const int N = in_sizes[0] / F;          // 100000
    const int E = in_sizes[1] / 2;          // 1200000
    (void)F;

    const int* src = ei;
    const int* dst = ei + E;
    const int T  = E + N;                   // CSR entries incl self-loops
    const int NB = (N + NPB - 1) / NPB;     // buckets (391)

    // ws layout, each segment 256B-aligned
    char* w8 = (char*)d_ws;
    auto alloc = [&](size_t bytes) {
        char* p = w8;
        w8 += (bytes + 255) & ~(size_t)255;
        return p;
    };
    int*   bcnt    = (int*)  alloc((size_t)NB * 4);
    int*   cbase   = (int*)  alloc((size_t)NB * 4);
    int*   row_ptr = (int*)  alloc((size_t)(N + 1) * 4);
    float* dinv    = (float*)alloc((size_t)N * 4);
    unsigned int* bin2 = (unsigned int*)alloc((size_t)NB * CAP2B * 4); // 5.4 MB
    int*   csr_src = (int*)  alloc((size_t)T * 4);                     // 5.2 MB
    unsigned short* p16 = (unsigned short*)alloc((size_t)N * CPAD * 2);
    unsigned int*   y16 = (unsigned int*)  alloc((size_t)N * 32 * 4);

    const int B = 256;
    const int NT = (E + TILE2 - 1) / TILE2;  // 586 binning tiles

    k_zero <<<(NB + B - 1) / B, B, 0, stream>>>(bcnt, NB);
    k_binD <<<NT, B, 0, stream>>>(src, dst, bcnt, bin2, E, NB);
    k_bscan<<<1, 512, 0, stream>>>(bcnt, cbase, row_ptr, NB, N, T);
    k_build<<<NB, B, 0, stream>>>(bcnt, cbase, bin2, row_ptr, dinv, csr_src, N);

    k_proj <<<(N + PTILE - 1) / PTILE, B, 0, stream>>>(x, W, dinv, p16, N, C);

    k_hop1 <<<(N + 3) / 4, B, 0, stream>>>(row_ptr, csr_src, dinv,
                                           (const unsigned int*)p16, y16, N);

    k_hop2_lsm<<<(N + 3) / 4, B, 0, stream>>>(row_ptr, csr_src, dinv,
                                              y16, b, out, N, C);
}